// Round 4
// baseline (243.297 us; speedup 1.0000x reference)
//
#include <hip/hip_runtime.h>

// NearestEmbed (VQ argmin + gather), MI355X gfx950.  Round 7.
// x: (B=64, D=64, H=32, W=32) fp32 ; emb: (D=64, K=512) fp32
// out0: quant (B,D,H,W) fp32 ; out1: argmin (B,H,W) as fp32.
//
// R7 (R6 post-mortem: 8x16 tile spilled (WRITE 16.7->37.8MB, VGPR capped
// 128); R5's LDS pipe floor 41us > VALU floor 27us and only 59% utilized):
//  * NO LDS operands: e-side reads are 2x coalesced 512B segments/wave from
//    L1/L2 (emb 128KB hot); x-side is 2 distinct float4/wave (broadcast).
//    LDS pipe idle; no mid-kernel barriers at all.
//  * 1024 blocks x 256 thr (64 rows, CK=256, NCH=2, tile 8x8) -> 4 blk/CU,
//    16 waves/CU = 2x R5 TLP. Purely VALU-bound, floor 27.3us.
//  * ||e||^2 fused into hot loop on already-loaded ev regs (+8 FMA/step),
//    deleting the e2 prologue (128KB/block reads), its LDS and barrier.
//    Same d-ascending fmaf chain -> scores bit-identical -> absmax 0.
//  * Regs ~124 <= 128 cap: e-side depth-1 prefetch, x demand-loaded.

constexpr int D    = 64;
constexpr int K    = 512;
constexpr int HW   = 1024;   // 32*32
constexpr int ROWS = 64;     // rows per block
constexpr int CK   = 256;    // codes per chunk
constexpr int NCH  = K / CK; // 2

__global__ __launch_bounds__(256, 4) void vq_kernel(
    const float* __restrict__ x,
    const float* __restrict__ emb,
    float* __restrict__ out_q,
    float* __restrict__ out_idx)
{
    __shared__ int kfin[ROWS];   // 256 B — only LDS in the kernel

    const int tid = threadIdx.x;
    const int ct  = tid & 31;    // 32 code-threads: codes 4ct+c and 128+4ct+c
    const int rg  = tid >> 5;    // 8 row-groups: rows 4rg+r and 32+4rg+r
    const int r0  = blockIdx.x * ROWS;
    const int b   = r0 >> 10;
    const int n0  = r0 & (HW - 1);

    // x stream for this thread's 8 rows: two float4 at +0 and +128B, step 4KB/d
    const float* xp = x + ((size_t)b * D) * HW + n0 + (rg << 2);

    float best[8];
    int   bidx[8];
    #pragma unroll
    for (int r = 0; r < 8; ++r) { best[r] = 3.4e38f; bidx[r] = 0; }

    #pragma unroll 1
    for (int ch = 0; ch < NCH; ++ch) {
        // e stream: two float4 at +0 and +512B, step 2KB/d (coalesced 512B/wave)
        const float* ep = emb + ch * CK + (ct << 2);

        float acc[8][8];
        #pragma unroll
        for (int r = 0; r < 8; ++r)
            #pragma unroll
            for (int c = 0; c < 8; ++c) acc[r][c] = 0.f;
        float e2a[8];
        #pragma unroll
        for (int c = 0; c < 8; ++c) e2a[c] = 0.f;

        auto step = [&](const float4& xa, const float4& xb,
                        const float4& ea, const float4& eb) {
            const float* xaf = reinterpret_cast<const float*>(&xa);
            const float* xbf = reinterpret_cast<const float*>(&xb);
            const float* eaf = reinterpret_cast<const float*>(&ea);
            const float* ebf = reinterpret_cast<const float*>(&eb);
            #pragma unroll
            for (int c = 0; c < 4; ++c) {              // fused ||e||^2 (same
                e2a[c]     = fmaf(eaf[c], eaf[c], e2a[c]);      // d-ascending
                e2a[4 + c] = fmaf(ebf[c], ebf[c], e2a[4 + c]);  // fmaf chain)
            }
            #pragma unroll
            for (int r = 0; r < 4; ++r) {
                const float x0 = xaf[r];
                const float x1 = xbf[r];
                #pragma unroll
                for (int c = 0; c < 4; ++c) {
                    acc[r][c]         = fmaf(x0, eaf[c], acc[r][c]);
                    acc[r][4 + c]     = fmaf(x0, ebf[c], acc[r][4 + c]);
                    acc[r + 4][c]     = fmaf(x1, eaf[c], acc[r + 4][c]);
                    acc[r + 4][4 + c] = fmaf(x1, ebf[c], acc[r + 4][4 + c]);
                }
            }
        };

        float4 ea = *reinterpret_cast<const float4*>(ep);
        float4 eb = *reinterpret_cast<const float4*>(ep + 128);

        #pragma unroll 9
        for (int d = 0; d < D - 1; ++d) {            // 63 = 7*9 iterations
            const float4 xa  = *reinterpret_cast<const float4*>(xp + (size_t)d * HW);
            const float4 xb  = *reinterpret_cast<const float4*>(xp + (size_t)d * HW + 32);
            const float4 nea = *reinterpret_cast<const float4*>(ep + (d + 1) * K);
            const float4 neb = *reinterpret_cast<const float4*>(ep + (d + 1) * K + 128);
            step(xa, xb, ea, eb);
            ea = nea; eb = neb;
        }
        {   // d = 63
            const float4 xa = *reinterpret_cast<const float4*>(xp + (size_t)(D - 1) * HW);
            const float4 xb = *reinterpret_cast<const float4*>(xp + (size_t)(D - 1) * HW + 32);
            step(xa, xb, ea, eb);
        }

        // scoring: s = e2 - 2*acc (identical fp32 chain); per row, codes
        // scanned ascending (group 0: kb+c, group 1: kb+128+c) -> strict <
        // keeps first index; chunks ascend.
        const int kb = ch * CK + (ct << 2);
        #pragma unroll
        for (int r = 0; r < 8; ++r) {
            #pragma unroll
            for (int c = 0; c < 4; ++c) {
                const float s = fmaf(-2.f, acc[r][c], e2a[c]);
                if (s < best[r]) { best[r] = s; bidx[r] = kb + c; }
            }
            #pragma unroll
            for (int c = 0; c < 4; ++c) {
                const float s = fmaf(-2.f, acc[r][4 + c], e2a[4 + c]);
                if (s < best[r]) { best[r] = s; bidx[r] = kb + 128 + c; }
            }
        }
    }

    // ---- merge across 32 code-threads (lane bits 0..4 = ct bits) ----
    #pragma unroll
    for (int m = 1; m < 32; m <<= 1) {
        #pragma unroll
        for (int r = 0; r < 8; ++r) {
            const float ob = __shfl_xor(best[r], m, 64);
            const int   oi = __shfl_xor(bidx[r], m, 64);
            if (ob < best[r] || (ob == best[r] && oi < bidx[r])) {
                best[r] = ob; bidx[r] = oi;   // lowest index wins exact ties
            }
        }
    }

    if (ct == 0) {   // lanes 0 and 32 of each wave hold their rg's rows
        #pragma unroll
        for (int r = 0; r < 4; ++r) {
            kfin[(rg << 2) + r]      = bidx[r];
            kfin[32 + (rg << 2) + r] = bidx[4 + r];
        }
    }
    __syncthreads();

    // coalesced argmin store (256 B per block)
    if (tid < ROWS)
        __builtin_nontemporal_store((float)kfin[tid], &out_idx[r0 + tid]);

    // ---- epilogue: gather emb column, coalesced nontemporal stores ----
    const int row = tid & 63;
    const int dg  = tid >> 6;            // 4 threads/row, 16 d-planes each
    const int kq  = kfin[row];
    float* oq = out_q + ((size_t)b * D) * HW + n0 + row;
    #pragma unroll
    for (int j = 0; j < 16; ++j) {
        const int d = (dg << 4) + j;
        // emb gather per-lane scattered 4B but L1/L2-hot (128 KB table);
        // stores: consecutive rows across lanes -> full 256B lines.
        __builtin_nontemporal_store(emb[d * K + kq], &oq[(size_t)d * HW]);
    }
}

extern "C" void kernel_launch(void* const* d_in, const int* in_sizes, int n_in,
                              void* d_out, int out_size, void* d_ws, size_t ws_size,
                              hipStream_t stream)
{
    const float* x   = (const float*)d_in[0];   // 4194304 floats
    const float* emb = (const float*)d_in[1];   // 32768 floats

    float* out_q   = (float*)d_out;                     // 4194304 floats
    float* out_idx = out_q + (size_t)64 * 64 * 1024;    // 65536 floats

    // 65536 rows / 64 rows-per-block = 1024 blocks of 256 threads
    // (no operand LDS -> 4 blocks/CU, 16 waves/CU, 4 waves/SIMD)
    vq_kernel<<<1024, 256, 0, stream>>>(x, emb, out_q, out_idx);
}

// Round 5
// 141.462 us; speedup vs baseline: 1.7199x; 1.7199x over previous
//
#include <hip/hip_runtime.h>

// NearestEmbed (VQ argmin + gather), MI355X gfx950.  Round 8.
// x: (B=64, D=64, H=32, W=32) fp32 ; emb: (D=64, K=512) fp32
// out0: quant (B,D,H,W) fp32 ; out1: argmin (B,H,W) as fp32.
//
// R8 (R7 post-mortem: the step-lambda with float4& params defeated SROA ->
// acc tile in scratch (VGPR 64, WRITE 297MB). Geometry was never tested.)
//  * Same all-global plan as R7: NO operand LDS, e-side = two coalesced
//    512B L1/L2-hot segments per wave per d, x-side = two broadcast lines.
//    LDS pipe idle (R5's 41us floor removed); VALU-bound, floor ~30.7us.
//  * Hot body inlined R5-style: direct float4 locals + compile-time-indexed
//    scalar copies. No lambda, no reference params, no manual prefetch.
//  * 1024 blocks x 256 thr (64 rows, CK=256, NCH=2, 8x8 tile) -> 4 blk/CU,
//    16 waves/CU = 4 waves/SIMD.
//  * ||e||^2 fused on in-register e values (d-ascending fmaf chain, as is
//    the acc chain); ascending code scan + index-compare merge keeps
//    first-index tie-break -> argmin matches reference exactly.

constexpr int D    = 64;
constexpr int K    = 512;
constexpr int HW   = 1024;   // 32*32
constexpr int ROWS = 64;     // rows per block
constexpr int CK   = 256;    // codes per chunk
constexpr int NCH  = K / CK; // 2

__global__ __launch_bounds__(256, 4) void vq_kernel(
    const float* __restrict__ x,
    const float* __restrict__ emb,
    float* __restrict__ out_q,
    float* __restrict__ out_idx)
{
    __shared__ int kfin[ROWS];   // 256 B — only LDS in the kernel

    const int tid = threadIdx.x;
    const int ct  = tid & 31;    // 32 code-threads: codes 4ct+c and 128+4ct+c
    const int rg  = tid >> 5;    // 8 row-groups: rows 4rg+r and 32+4rg+r
    const int r0  = blockIdx.x * ROWS;
    const int b   = r0 >> 10;
    const int n0  = r0 & (HW - 1);

    // x stream for this thread's rows: float4 at +0 and +128B, step 4KB per d
    const float* xp = x + ((size_t)b * D) * HW + n0 + (rg << 2);

    float best[8];
    int   bidx[8];
    #pragma unroll
    for (int r = 0; r < 8; ++r) { best[r] = 3.4e38f; bidx[r] = 0; }

    #pragma unroll 1
    for (int ch = 0; ch < NCH; ++ch) {
        // e stream: float4 at +0 and +512B, step 2KB per d (512B/wave coalesced)
        const float* ep = emb + ch * CK + (ct << 2);

        float acc[8][8];
        #pragma unroll
        for (int r = 0; r < 8; ++r)
            #pragma unroll
            for (int c = 0; c < 8; ++c) acc[r][c] = 0.f;
        float e2a[8];
        #pragma unroll
        for (int c = 0; c < 8; ++c) e2a[c] = 0.f;

        #pragma unroll 4
        for (int d = 0; d < D; ++d) {
            const float4 xa = *reinterpret_cast<const float4*>(xp + (size_t)d * HW);
            const float4 xb = *reinterpret_cast<const float4*>(xp + (size_t)d * HW + 32);
            const float4 ea = *reinterpret_cast<const float4*>(ep + d * K);
            const float4 eb = *reinterpret_cast<const float4*>(ep + d * K + 128);

            const float xaf[4] = {xa.x, xa.y, xa.z, xa.w};
            const float xbf[4] = {xb.x, xb.y, xb.z, xb.w};
            const float eaf[4] = {ea.x, ea.y, ea.z, ea.w};
            const float ebf[4] = {eb.x, eb.y, eb.z, eb.w};

            #pragma unroll
            for (int c = 0; c < 4; ++c) {              // fused ||e||^2,
                e2a[c]     = fmaf(eaf[c], eaf[c], e2a[c]);     // d-ascending
                e2a[4 + c] = fmaf(ebf[c], ebf[c], e2a[4 + c]); // fmaf chain
            }
            #pragma unroll
            for (int r = 0; r < 4; ++r) {
                const float x0 = xaf[r];
                const float x1 = xbf[r];
                #pragma unroll
                for (int c = 0; c < 4; ++c) {
                    acc[r][c]         = fmaf(x0, eaf[c], acc[r][c]);
                    acc[r][4 + c]     = fmaf(x0, ebf[c], acc[r][4 + c]);
                    acc[r + 4][c]     = fmaf(x1, eaf[c], acc[r + 4][c]);
                    acc[r + 4][4 + c] = fmaf(x1, ebf[c], acc[r + 4][4 + c]);
                }
            }
        }

        // scoring: s = e2 - 2*acc; per row, codes scanned ascending
        // (kb+c then kb+128+c), strict < => first index; chunks ascend.
        const int kb = ch * CK + (ct << 2);
        #pragma unroll
        for (int r = 0; r < 8; ++r) {
            #pragma unroll
            for (int c = 0; c < 4; ++c) {
                const float s = fmaf(-2.f, acc[r][c], e2a[c]);
                if (s < best[r]) { best[r] = s; bidx[r] = kb + c; }
            }
            #pragma unroll
            for (int c = 0; c < 4; ++c) {
                const float s = fmaf(-2.f, acc[r][4 + c], e2a[4 + c]);
                if (s < best[r]) { best[r] = s; bidx[r] = kb + 128 + c; }
            }
        }
    }

    // ---- merge across 32 code-threads (lane bits 0..4 = ct bits) ----
    #pragma unroll
    for (int m = 1; m < 32; m <<= 1) {
        #pragma unroll
        for (int r = 0; r < 8; ++r) {
            const float ob = __shfl_xor(best[r], m, 64);
            const int   oi = __shfl_xor(bidx[r], m, 64);
            if (ob < best[r] || (ob == best[r] && oi < bidx[r])) {
                best[r] = ob; bidx[r] = oi;   // lowest index wins exact ties
            }
        }
    }

    if (ct == 0) {   // lanes 0 and 32 of each wave hold their rg's rows
        #pragma unroll
        for (int r = 0; r < 4; ++r) {
            kfin[(rg << 2) + r]      = bidx[r];
            kfin[32 + (rg << 2) + r] = bidx[4 + r];
        }
    }
    __syncthreads();

    // coalesced argmin store (256 B per block)
    if (tid < ROWS)
        __builtin_nontemporal_store((float)kfin[tid], &out_idx[r0 + tid]);

    // ---- epilogue: gather emb column, coalesced nontemporal stores ----
    const int row = tid & 63;
    const int dg  = tid >> 6;            // 4 threads/row, 16 d-planes each
    const int kq  = kfin[row];
    float* oq = out_q + ((size_t)b * D) * HW + n0 + row;
    #pragma unroll
    for (int j = 0; j < 16; ++j) {
        const int d = (dg << 4) + j;
        // emb gather per-lane scattered 4B but L1/L2-hot (128 KB table);
        // stores: consecutive rows across lanes -> full 256B lines.
        __builtin_nontemporal_store(emb[d * K + kq], &oq[(size_t)d * HW]);
    }
}

extern "C" void kernel_launch(void* const* d_in, const int* in_sizes, int n_in,
                              void* d_out, int out_size, void* d_ws, size_t ws_size,
                              hipStream_t stream)
{
    const float* x   = (const float*)d_in[0];   // 4194304 floats
    const float* emb = (const float*)d_in[1];   // 32768 floats

    float* out_q   = (float*)d_out;                     // 4194304 floats
    float* out_idx = out_q + (size_t)64 * 64 * 1024;    // 65536 floats

    // 65536 rows / 64 rows-per-block = 1024 blocks of 256 threads
    // (no operand LDS -> 4 blocks/CU, 16 waves/CU, 4 waves/SIMD)
    vq_kernel<<<1024, 256, 0, stream>>>(x, emb, out_q, out_idx);
}

// Round 6
// 135.093 us; speedup vs baseline: 1.8010x; 1.0471x over previous
//
#include <hip/hip_runtime.h>

// NearestEmbed (VQ argmin + gather), MI355X gfx950.  Round 9.
// x: (B=64, D=64, H=32, W=32) fp32 ; emb: (D=64, K=512) fp32
// out0: quant (B,D,H,W) fp32 ; out1: argmin (B,H,W) as fp32.
//
// R9 (R8 post-mortem: all-global hot loop spilled acc again (VGPR=64,
// WRITE 53.5MB) -- 4 pipelined global loads/step + 88 persistent regs
// exceeds the 128 cap; R5's LDS-fed loop was codegen-clean but LDS-bound):
//  * HYBRID: x tile (16KB) in LDS -- broadcast reads, imm-offset addressing,
//    2 ds_read/step (LDS floor ~15us, not binding). e from global -- two
//    coalesced 512B L1/L2-hot loads/step, only 2 loads to pipeline.
//  * launch_bounds(256,3): 168-reg headroom, far from the spill cliff.
//  * Hot FMAs macro-unrolled with literal indices + float4 member access
//    (max SROA-safety). ||e||^2 fused on in-register e (d-ascending chain).
//  * One barrier total (after x staging). No mid-kernel syncs.
//  * Scan/merge order identical to R8 (exact): ascending codes, strict <,
//    index tie-break in shfl merge -> argmin matches reference exactly.

constexpr int D    = 64;
constexpr int K    = 512;
constexpr int HW   = 1024;   // 32*32
constexpr int ROWS = 64;     // rows per block
constexpr int CK   = 256;    // codes per chunk
constexpr int NCH  = K / CK; // 2

__device__ __forceinline__ void gload16(const float* g, float* l) {
    __builtin_amdgcn_global_load_lds(
        (const __attribute__((address_space(1))) void*)g,
        (__attribute__((address_space(3))) void*)l,
        16, 0, 0);
}

__global__ __launch_bounds__(256, 3) void vq_kernel(
    const float* __restrict__ x,
    const float* __restrict__ emb,
    float* __restrict__ out_q,
    float* __restrict__ out_idx)
{
    __shared__ float xs[D][ROWS];   // 16 KB  xs[d][row]
    __shared__ int   kfin[ROWS];    // 256 B

    const int tid = threadIdx.x;
    const int ct  = tid & 31;    // 32 code-threads: codes 4ct+c and 128+4ct+c
    const int rg  = tid >> 5;    // 8 row-groups: rows 4rg+r and 32+4rg+r
    const int r0  = blockIdx.x * ROWS;
    const int b   = r0 >> 10;
    const int n0  = r0 & (HW - 1);

    // ---- stage x tile (64 d x 64 rows) via global_load_lds, once ----
    // dest byte = li*16 (linear = wave-uniform base + lane*16).
    {
        const float* xg = x + ((size_t)b * D) * HW + n0;
        #pragma unroll
        for (int p = 0; p < 4; ++p) {
            const int li = p * 256 + tid;
            const int d  = li >> 4;            // 16 float4 per 64-float d-row
            const int r4 = (li & 15) << 2;
            gload16(xg + (size_t)d * HW + r4, &xs[d][r4]);
        }
    }
    __syncthreads();   // drains vmcnt: xs visible. Only barrier before epilogue.

    float best[8];
    int   bidx[8];
    #pragma unroll
    for (int r = 0; r < 8; ++r) { best[r] = 3.4e38f; bidx[r] = 0; }

    #pragma unroll 1
    for (int ch = 0; ch < NCH; ++ch) {
        // e stream: float4 at +0 and +512B, step 2KB/d. Lanes 0-31 -> one
        // coalesced 512B segment; lanes 32-63 duplicate it (broadcast).
        const float* ep = emb + ch * CK + (ct << 2);

        float acc[8][8];
        #pragma unroll
        for (int r = 0; r < 8; ++r)
            #pragma unroll
            for (int c = 0; c < 8; ++c) acc[r][c] = 0.f;
        float e2a[8];
        #pragma unroll
        for (int c = 0; c < 8; ++c) e2a[c] = 0.f;

        #pragma unroll 2
        for (int d = 0; d < D; ++d) {
            // x: two broadcast LDS reads (2 distinct addrs/wave, 0 conflicts)
            const float4 xa = *reinterpret_cast<const float4*>(&xs[d][rg << 2]);
            const float4 xb = *reinterpret_cast<const float4*>(&xs[d][32 + (rg << 2)]);
            // e: two coalesced global loads (L1/L2-hot, 128KB table)
            const float4 ea = *reinterpret_cast<const float4*>(ep + d * K);
            const float4 eb = *reinterpret_cast<const float4*>(ep + d * K + 128);

            // fused ||e||^2, d-ascending fmaf chain (matches reference)
            e2a[0] = fmaf(ea.x, ea.x, e2a[0]);
            e2a[1] = fmaf(ea.y, ea.y, e2a[1]);
            e2a[2] = fmaf(ea.z, ea.z, e2a[2]);
            e2a[3] = fmaf(ea.w, ea.w, e2a[3]);
            e2a[4] = fmaf(eb.x, eb.x, e2a[4]);
            e2a[5] = fmaf(eb.y, eb.y, e2a[5]);
            e2a[6] = fmaf(eb.z, eb.z, e2a[6]);
            e2a[7] = fmaf(eb.w, eb.w, e2a[7]);

            // 64 FMAs, all-literal indices (SROA-safe)
#define ROWFMA(r, xv)                                  \
            acc[r][0] = fmaf(xv, ea.x, acc[r][0]);     \
            acc[r][1] = fmaf(xv, ea.y, acc[r][1]);     \
            acc[r][2] = fmaf(xv, ea.z, acc[r][2]);     \
            acc[r][3] = fmaf(xv, ea.w, acc[r][3]);     \
            acc[r][4] = fmaf(xv, eb.x, acc[r][4]);     \
            acc[r][5] = fmaf(xv, eb.y, acc[r][5]);     \
            acc[r][6] = fmaf(xv, eb.z, acc[r][6]);     \
            acc[r][7] = fmaf(xv, eb.w, acc[r][7]);
            ROWFMA(0, xa.x)
            ROWFMA(1, xa.y)
            ROWFMA(2, xa.z)
            ROWFMA(3, xa.w)
            ROWFMA(4, xb.x)
            ROWFMA(5, xb.y)
            ROWFMA(6, xb.z)
            ROWFMA(7, xb.w)
#undef ROWFMA
        }

        // scoring: s = e2 - 2*acc; per row, codes scanned ascending
        // (kb+c then kb+128+c), strict < => first index; chunks ascend.
        const int kb = ch * CK + (ct << 2);
        #pragma unroll
        for (int r = 0; r < 8; ++r) {
            #pragma unroll
            for (int c = 0; c < 4; ++c) {
                const float s = fmaf(-2.f, acc[r][c], e2a[c]);
                if (s < best[r]) { best[r] = s; bidx[r] = kb + c; }
            }
            #pragma unroll
            for (int c = 0; c < 4; ++c) {
                const float s = fmaf(-2.f, acc[r][4 + c], e2a[4 + c]);
                if (s < best[r]) { best[r] = s; bidx[r] = kb + 128 + c; }
            }
        }
    }

    // ---- merge across 32 code-threads (lane bits 0..4 = ct bits) ----
    #pragma unroll
    for (int m = 1; m < 32; m <<= 1) {
        #pragma unroll
        for (int r = 0; r < 8; ++r) {
            const float ob = __shfl_xor(best[r], m, 64);
            const int   oi = __shfl_xor(bidx[r], m, 64);
            if (ob < best[r] || (ob == best[r] && oi < bidx[r])) {
                best[r] = ob; bidx[r] = oi;   // lowest index wins exact ties
            }
        }
    }

    if (ct == 0) {   // lanes 0 and 32 of each wave hold their rg's rows
        #pragma unroll
        for (int r = 0; r < 4; ++r) {
            kfin[(rg << 2) + r]      = bidx[r];
            kfin[32 + (rg << 2) + r] = bidx[4 + r];
        }
    }
    __syncthreads();

    // coalesced argmin store (256 B per block)
    if (tid < ROWS)
        __builtin_nontemporal_store((float)kfin[tid], &out_idx[r0 + tid]);

    // ---- epilogue: gather emb column, coalesced nontemporal stores ----
    const int row = tid & 63;
    const int dg  = tid >> 6;            // 4 threads/row, 16 d-planes each
    const int kq  = kfin[row];
    float* oq = out_q + ((size_t)b * D) * HW + n0 + row;
    #pragma unroll
    for (int j = 0; j < 16; ++j) {
        const int d = (dg << 4) + j;
        // emb gather per-lane scattered 4B but L1/L2-hot (128 KB table);
        // stores: consecutive rows across lanes -> full 256B lines.
        __builtin_nontemporal_store(emb[d * K + kq], &oq[(size_t)d * HW]);
    }
}

extern "C" void kernel_launch(void* const* d_in, const int* in_sizes, int n_in,
                              void* d_out, int out_size, void* d_ws, size_t ws_size,
                              hipStream_t stream)
{
    const float* x   = (const float*)d_in[0];   // 4194304 floats
    const float* emb = (const float*)d_in[1];   // 32768 floats

    float* out_q   = (float*)d_out;                     // 4194304 floats
    float* out_idx = out_q + (size_t)64 * 64 * 1024;    // 65536 floats

    // 65536 rows / 64 rows-per-block = 1024 blocks of 256 threads
    // (LDS 16.6 KB -> 3-4 blocks/CU, 12-16 waves/CU)
    vq_kernel<<<1024, 256, 0, stream>>>(x, emb, out_q, out_idx);
}